// Round 1
// baseline (133.040 us; speedup 1.0000x reference)
//
#include <hip/hip_runtime.h>
#include <math.h>

// Only out[mask_idx] (~320 agent nodes of 50000) is read downstream, so only
// edges whose dst is a masked node matter (~5120 of 800000).
//
// Round-5: kill the replicated per-block setup tax. Previous version ran 782
// blocks, each zeroing a 6.3KB bitmap, staging 4.5K weight floats, inserting
// 320 mask bits, and doing a 20-iteration LDS search per hit edge to recover
// the agent slot. This version:
//   (a) replaces bitmap + slot-search with ONE 2048-entry LDS hash table
//       keyed by node, value = min agent slot, packed (node<<9)|slot.
//       Membership test and slot recovery are the same ~1.2-probe lookup;
//       the queue stores (edge<<9)|slot so phase 3 has zero search.
//   (b) 4096 edges/block -> 196 blocks (was 782): all fixed setup drops 4x.
//       Queue capacity == edges/block, so overflow is impossible.
// Workspace layout unchanged (21.3 KB aggr_c + deg_c).

#define HASH_SZ   2048
#define HASH_MASK 2047
#define HEMPTY    0xFFFFFFFFu
#define QUADS_PB  1024        // int4 dst quads per block -> 4096 edges/block
#define QCAP      4096        // == edges per block -> can never overflow

__global__ __launch_bounds__(256) void k_fused(
    const int* __restrict__ srcp, const int* __restrict__ dstp,
    const int4* __restrict__ dst4, int nquad, int E,
    const float* __restrict__ x, const float* __restrict__ edge_attr,
    const float* __restrict__ w1, const float* __restrict__ b1,
    const float* __restrict__ w2, const float* __restrict__ b2,
    const int* __restrict__ mask_idx, int A,
    float* __restrict__ aggr_c, int* __restrict__ deg_c) {
    __shared__ unsigned s_hash[HASH_SZ]; // (node<<9)|minslot, HEMPTY = free
    __shared__ float s_w2[4096];   // [16 j][256 io]
    __shared__ float s_b2[256];
    __shared__ float s_w1[128];    // [8 k][16 j]
    __shared__ float s_b1[16];
    __shared__ unsigned s_q[QCAP]; // (edge<<9)|slot
    __shared__ int   s_qcnt;
    __shared__ float s_ea[16][8];
    __shared__ float s_x[16][16];
    __shared__ float s_h[16][16];

    int tid = threadIdx.x;
    if (tid == 0) s_qcnt = 0;
    #pragma unroll
    for (int i = tid; i < HASH_SZ; i += 256) s_hash[i] = HEMPTY;
    // stage weights concurrently with hash init (independent)
    for (int k = tid; k < 4096; k += 256) s_w2[k] = w2[k];
    s_b2[tid] = b2[tid];
    if (tid < 128) s_w1[tid] = w1[tid];
    if (tid < 16)  s_b1[tid] = b1[tid];
    __syncthreads();               // hash cleared before inserts

    // Insert masked nodes. atomicMin on the packed word dedups duplicate
    // agents to the minimum agent index (rep slot), matching k_head's search.
    for (int a = tid; a < A; a += 256) {
        int node = mask_idx[a];               // node < 50000, a < 512
        unsigned pk = ((unsigned)node << 9) | (unsigned)a;
        unsigned h = ((unsigned)node * 2654435761u) >> 21;   // 11 bits
        for (;;) {
            unsigned cur = atomicCAS(&s_hash[h], HEMPTY, pk);
            if (cur == HEMPTY) break;
            if ((cur >> 9) == (unsigned)node) { atomicMin(&s_hash[h], pk); break; }
            h = (h + 1) & HASH_MASK;
        }
    }
    __syncthreads();

    // Phase 2: scan this block's 4096 edges; hash-probe dst; queue hits
    // with their slot already resolved. Table is read-only here.
    auto probe = [&](int node, int e) {
        unsigned h = ((unsigned)node * 2654435761u) >> 21;
        for (;;) {
            unsigned cur = s_hash[h];
            if (cur == HEMPTY) return;
            if ((cur >> 9) == (unsigned)node) {
                int p = atomicAdd(&s_qcnt, 1);
                s_q[p] = ((unsigned)e << 9) | (cur & 511u);
                return;
            }
            h = (h + 1) & HASH_MASK;
        }
    };
    int q0 = blockIdx.x * QUADS_PB;
    #pragma unroll
    for (int it = 0; it < 4; ++it) {
        int q = q0 + it * 256 + tid;
        if (q < nquad) {
            int4 d = dst4[q];
            int e0 = q * 4;
            probe(d.x, e0);
            probe(d.y, e0 + 1);
            probe(d.z, e0 + 2);
            probe(d.w, e0 + 3);
        }
    }
    // tail edges if E % 4 != 0 (none for E=800000; safety)
    if (blockIdx.x == 0 && tid == 0)
        for (int e = nquad * 4; e < E; ++e) probe(dstp[e], e);
    __syncthreads();
    int nq = s_qcnt; if (nq > QCAP) nq = QCAP;   // unreachable clamp, safety
    if (nq == 0) return;                          // uniform

    // Phase 3: process queue, 16 edges x 16 out-lanes per chunk. Slot comes
    // straight from the queue word — no search, no extra barrier.
    int el = tid >> 4;     // edge slot 0..15
    int o  = tid & 15;     // output channel 0..15
    for (int base = 0; base < nq; base += 16) {
        int idx = base + el;
        bool valid = (idx < nq);
        int e = 0, slot = 0;
        if (valid) {
            unsigned pk = s_q[idx];
            e = (int)(pk >> 9);
            slot = (int)(pk & 511u);
            if (o < 8) s_ea[el][o] = edge_attr[(long)e * 8 + o];
            s_x[el][o] = x[(long)srcp[e] * 16 + o];
        }
        __syncthreads();
        if (valid) {
            // h[el][o] = relu(b1[o] + ea . w1[:,o])
            float hj = s_b1[o];
            #pragma unroll
            for (int k = 0; k < 8; ++k) hj += s_ea[el][k] * s_w1[k * 16 + o];
            s_h[el][o] = hj > 0.f ? hj : 0.f;
        }
        __syncthreads();
        if (valid) {
            float hr[16], xr[16];
            #pragma unroll
            for (int j = 0; j < 16; ++j) hr[j] = s_h[el][j];
            #pragma unroll
            for (int i = 0; i < 16; ++i) xr[i] = s_x[el][i];
            // msg[o] = sum_i x_i * (b2[i,o] + sum_j h_j * w2[j, i*16+o])
            float m = 0.f;
            #pragma unroll
            for (int i = 0; i < 16; ++i) {
                float tacc = s_b2[i * 16 + o];
                #pragma unroll
                for (int j = 0; j < 16; ++j) tacc += hr[j] * s_w2[j * 256 + i * 16 + o];
                m += xr[i] * tacc;
            }
            atomicAdd(&aggr_c[slot * 16 + o], m);
            if (o == 0) atomicAdd(&deg_c[slot], 1);
        }
        __syncthreads();
    }
}

// One block (1 wave) per agent: combine + 3-layer ELU MLP head.
__global__ __launch_bounds__(64) void k_head(
    const int* __restrict__ mask_idx, int A, const float* __restrict__ action,
    const float* __restrict__ x,
    const float* __restrict__ aggr_c, const int* __restrict__ deg_c,
    const float* __restrict__ root, const float* __restrict__ bias,
    const float* __restrict__ fc1_w, const float* __restrict__ fc1_b,
    const float* __restrict__ fc2_w, const float* __restrict__ fc2_b,
    const float* __restrict__ fc3_w, const float* __restrict__ fc3_b,
    float* __restrict__ out) {
    __shared__ float xm[17];
    __shared__ float y1[64];
    int a = blockIdx.x;
    int t = threadIdx.x;
    int node = mask_idx[a];
    // rep slot = first agent index with this node (duplicate agents share)
    int best = 0x7fffffff;
    for (int i = t; i < A; i += 64)
        if (mask_idx[i] == node && i < best) best = i;
    #pragma unroll
    for (int off = 32; off > 0; off >>= 1) {
        int o2 = __shfl_xor(best, off, 64);
        if (o2 < best) best = o2;
    }
    int s = best;
    if (t < 16) {
        float r = bias[t];
        #pragma unroll
        for (int i = 0; i < 16; ++i) r += x[(long)node * 16 + i] * root[i * 16 + t];
        float dg = (float)deg_c[s];
        if (dg < 1.f) dg = 1.f;
        xm[t] = aggr_c[s * 16 + t] / dg + r;
    } else if (t == 16) {
        xm[16] = action[a];
    }
    __syncthreads();
    float v = fc1_b[t];
    #pragma unroll
    for (int k = 0; k < 17; ++k) v += xm[k] * fc1_w[k * 64 + t];
    v = v > 0.f ? v : expm1f(v);
    y1[t] = v;
    __syncthreads();
    float u = fc2_b[t];
    #pragma unroll
    for (int j = 0; j < 64; ++j) u += y1[j] * fc2_w[j * 64 + t];
    u = u > 0.f ? u : expm1f(u);
    float p = u * fc3_w[t];
    #pragma unroll
    for (int off = 32; off > 0; off >>= 1) p += __shfl_down(p, off, 64);
    if (t == 0) out[a] = p + fc3_b[0];
}

extern "C" void kernel_launch(void* const* d_in, const int* in_sizes, int n_in,
                              void* d_out, int out_size, void* d_ws, size_t ws_size,
                              hipStream_t stream) {
    const float* x      = (const float*)d_in[0];
    const int*   ei     = (const int*)  d_in[1];
    const float* ea     = (const float*)d_in[2];
    const int*   mask   = (const int*)  d_in[3];
    const float* action = (const float*)d_in[4];
    // d_in[5] = B (unused)
    const float* w1     = (const float*)d_in[6];
    const float* b1     = (const float*)d_in[7];
    const float* w2     = (const float*)d_in[8];
    const float* b2     = (const float*)d_in[9];
    const float* root   = (const float*)d_in[10];
    const float* bias   = (const float*)d_in[11];
    const float* fc1_w  = (const float*)d_in[12];
    const float* fc1_b  = (const float*)d_in[13];
    const float* fc2_w  = (const float*)d_in[14];
    const float* fc2_b  = (const float*)d_in[15];
    const float* fc3_w  = (const float*)d_in[16];
    const float* fc3_b  = (const float*)d_in[17];

    const int E = in_sizes[2] / 8;    // 800000
    const int A = in_sizes[4];        // 320

    const int* srcp = ei;
    const int* dstp = ei + E;

    // Workspace: [aggr_c A*16 f32][deg_c A i32]  (21.3 KB total)
    float* aggr  = (float*)d_ws;
    int*   deg_c = (int*)(aggr + (size_t)A * 16);
    size_t fixed_bytes = (size_t)A * 16 * 4 + (size_t)A * 4;

    const int nquad = E / 4;
    const int nblocks = (nquad + QUADS_PB - 1) / QUADS_PB;   // 196

    hipMemsetAsync(d_ws, 0, fixed_bytes, stream);
    k_fused<<<nblocks, 256, 0, stream>>>(srcp, dstp, (const int4*)dstp, nquad, E,
                                         x, ea, w1, b1, w2, b2, mask, A, aggr, deg_c);
    k_head<<<A, 64, 0, stream>>>(mask, A, action, x, aggr, deg_c,
                                 root, bias, fc1_w, fc1_b, fc2_w, fc2_b, fc3_w, fc3_b,
                                 (float*)d_out);
}

// Round 3
// 123.488 us; speedup vs baseline: 1.0774x; 1.0774x over previous
//
#include <hip/hip_runtime.h>
#include <math.h>

// Only out[mask_idx] (~320 agent nodes of 50000) is read downstream, so only
// edges whose dst is a masked node matter (~5120 of 800000).
//
// Round-6 post-mortem of round-5: 4096-edge blocks (196 blocks) collapsed the
// wave pool to ~4 waves/CU (<=1 block/CU) and serialized 4 dependent
// load+probe iterations per thread -> +9.4us. The scan is latency-bound; it
// needs the ~12 waves/CU the 782-block layout had.
//
// Round-6/7 (resubmit; round-2 bench was an infra failure, container died
// before running): keep EXACTLY the old per-thread scan critical path (1 int4
// + 4 probes) and the old total wave count (3128 waves, all CUs busy), but
// use 512-thread blocks (391 blocks, 2048 edges each) so the replicated
// per-block setup (hash init, w2/b2/w1 staging, mask inserts) is paid half as
// many times and spread over 2x threads. Keep the round-5 LDS hash table: it
// resolves the agent slot during the scan, so phase 3 has no search, no
// atomicMin, one fewer barrier. LDS ~39.5KB -> 4 blocks/CU capacity (not
// binding at 391/256 ~ 1.5 blocks/CU).

#define HASH_SZ   2048
#define HASH_MASK 2047
#define HEMPTY    0xFFFFFFFFu
#define NTHREADS  512
#define QUADS_PB  512         // 512 threads x 1 int4 = 2048 edges/block
#define QCAP      2080        // 2048 edges + tail margin (E%4 + safety)

__global__ __launch_bounds__(NTHREADS) void k_fused(
    const int* __restrict__ srcp, const int* __restrict__ dstp,
    const int4* __restrict__ dst4, int nquad, int E,
    const float* __restrict__ x, const float* __restrict__ edge_attr,
    const float* __restrict__ w1, const float* __restrict__ b1,
    const float* __restrict__ w2, const float* __restrict__ b2,
    const int* __restrict__ mask_idx, int A,
    float* __restrict__ aggr_c, int* __restrict__ deg_c) {
    __shared__ unsigned s_hash[HASH_SZ]; // (node<<9)|minslot, HEMPTY = free
    __shared__ float s_w2[4096];   // [16 j][256 io]
    __shared__ float s_b2[256];
    __shared__ float s_w1[128];    // [8 k][16 j]
    __shared__ float s_b1[16];
    __shared__ unsigned s_q[QCAP]; // (edge<<9)|slot
    __shared__ int   s_qcnt;
    __shared__ float s_ea[32][8];
    __shared__ float s_x[32][16];
    __shared__ float s_h[32][16];

    int tid = threadIdx.x;
    if (tid == 0) s_qcnt = 0;
    for (int i = tid; i < HASH_SZ; i += NTHREADS) s_hash[i] = HEMPTY;
    // stage weights concurrently with hash init (independent); float4 w2
    {
        const float4* w2v = (const float4*)w2;
        float4* s_w2v = (float4*)s_w2;
        for (int k = tid; k < 1024; k += NTHREADS) s_w2v[k] = w2v[k];
    }
    if (tid < 256) s_b2[tid] = b2[tid];
    if (tid < 128) s_w1[tid] = w1[tid];
    if (tid < 16)  s_b1[tid] = b1[tid];
    __syncthreads();               // hash cleared before inserts

    // Insert masked nodes. atomicMin on the packed word dedups duplicate
    // agents to the minimum agent index (rep slot), matching k_head's search.
    for (int a = tid; a < A; a += NTHREADS) {
        int node = mask_idx[a];               // node < 50000, a < 512
        unsigned pk = ((unsigned)node << 9) | (unsigned)a;
        unsigned h = ((unsigned)node * 2654435761u) >> 21;   // 11 bits
        for (;;) {
            unsigned cur = atomicCAS(&s_hash[h], HEMPTY, pk);
            if (cur == HEMPTY) break;
            if ((cur >> 9) == (unsigned)node) { atomicMin(&s_hash[h], pk); break; }
            h = (h + 1) & HASH_MASK;
        }
    }
    __syncthreads();

    // Phase 2: scan this block's 2048 edges; hash-probe dst; queue hits with
    // their slot already resolved. Table is read-only here; ~85% of probes
    // hit an empty slot immediately (load factor 320/2048).
    auto probe = [&](int node, int e) {
        unsigned h = ((unsigned)node * 2654435761u) >> 21;
        for (;;) {
            unsigned cur = s_hash[h];
            if (cur == HEMPTY) return;
            if ((cur >> 9) == (unsigned)node) {
                int p = atomicAdd(&s_qcnt, 1);
                if (p < QCAP) s_q[p] = ((unsigned)e << 9) | (cur & 511u);
                return;
            }
            h = (h + 1) & HASH_MASK;
        }
    };
    int q = blockIdx.x * QUADS_PB + tid;
    if (q < nquad) {
        int4 d = dst4[q];
        int e0 = q * 4;
        probe(d.x, e0);
        probe(d.y, e0 + 1);
        probe(d.z, e0 + 2);
        probe(d.w, e0 + 3);
    }
    // tail edges if E % 4 != 0 (none for E=800000; safety)
    if (blockIdx.x == 0 && tid == 0)
        for (int e = nquad * 4; e < E; ++e) probe(dstp[e], e);
    __syncthreads();
    int nq = s_qcnt; if (nq > QCAP) nq = QCAP;
    if (nq == 0) return;                          // uniform

    // Phase 3: process queue, 32 edges x 16 out-lanes per chunk. Slot comes
    // straight from the queue word — no search, no extra barrier. Average
    // block has ~6.5 hits -> exactly one chunk.
    int el = tid >> 4;     // edge slot 0..31
    int o  = tid & 15;     // output channel 0..15
    for (int base = 0; base < nq; base += 32) {
        int idx = base + el;
        bool valid = (idx < nq);
        int e = 0, slot = 0;
        if (valid) {
            unsigned pk = s_q[idx];
            e = (int)(pk >> 9);
            slot = (int)(pk & 511u);
            if (o < 8) s_ea[el][o] = edge_attr[(long)e * 8 + o];
            s_x[el][o] = x[(long)srcp[e] * 16 + o];
        }
        __syncthreads();
        if (valid) {
            // h[el][o] = relu(b1[o] + ea . w1[:,o])
            float hj = s_b1[o];
            #pragma unroll
            for (int k = 0; k < 8; ++k) hj += s_ea[el][k] * s_w1[k * 16 + o];
            s_h[el][o] = hj > 0.f ? hj : 0.f;
        }
        __syncthreads();
        if (valid) {
            float hr[16], xr[16];
            #pragma unroll
            for (int j = 0; j < 16; ++j) hr[j] = s_h[el][j];
            #pragma unroll
            for (int i = 0; i < 16; ++i) xr[i] = s_x[el][i];
            // msg[o] = sum_i x_i * (b2[i,o] + sum_j h_j * w2[j, i*16+o])
            float m = 0.f;
            #pragma unroll
            for (int i = 0; i < 16; ++i) {
                float tacc = s_b2[i * 16 + o];
                #pragma unroll
                for (int j = 0; j < 16; ++j) tacc += hr[j] * s_w2[j * 256 + i * 16 + o];
                m += xr[i] * tacc;
            }
            atomicAdd(&aggr_c[slot * 16 + o], m);
            if (o == 0) atomicAdd(&deg_c[slot], 1);
        }
        __syncthreads();
    }
}

// One block (1 wave) per agent: combine + 3-layer ELU MLP head.
__global__ __launch_bounds__(64) void k_head(
    const int* __restrict__ mask_idx, int A, const float* __restrict__ action,
    const float* __restrict__ x,
    const float* __restrict__ aggr_c, const int* __restrict__ deg_c,
    const float* __restrict__ root, const float* __restrict__ bias,
    const float* __restrict__ fc1_w, const float* __restrict__ fc1_b,
    const float* __restrict__ fc2_w, const float* __restrict__ fc2_b,
    const float* __restrict__ fc3_w, const float* __restrict__ fc3_b,
    float* __restrict__ out) {
    __shared__ float xm[17];
    __shared__ float y1[64];
    int a = blockIdx.x;
    int t = threadIdx.x;
    int node = mask_idx[a];
    // rep slot = first agent index with this node (duplicate agents share)
    int best = 0x7fffffff;
    for (int i = t; i < A; i += 64)
        if (mask_idx[i] == node && i < best) best = i;
    #pragma unroll
    for (int off = 32; off > 0; off >>= 1) {
        int o2 = __shfl_xor(best, off, 64);
        if (o2 < best) best = o2;
    }
    int s = best;
    if (t < 16) {
        float r = bias[t];
        #pragma unroll
        for (int i = 0; i < 16; ++i) r += x[(long)node * 16 + i] * root[i * 16 + t];
        float dg = (float)deg_c[s];
        if (dg < 1.f) dg = 1.f;
        xm[t] = aggr_c[s * 16 + t] / dg + r;
    } else if (t == 16) {
        xm[16] = action[a];
    }
    __syncthreads();
    float v = fc1_b[t];
    #pragma unroll
    for (int k = 0; k < 17; ++k) v += xm[k] * fc1_w[k * 64 + t];
    v = v > 0.f ? v : expm1f(v);
    y1[t] = v;
    __syncthreads();
    float u = fc2_b[t];
    #pragma unroll
    for (int j = 0; j < 64; ++j) u += y1[j] * fc2_w[j * 64 + t];
    u = u > 0.f ? u : expm1f(u);
    float p = u * fc3_w[t];
    #pragma unroll
    for (int off = 32; off > 0; off >>= 1) p += __shfl_down(p, off, 64);
    if (t == 0) out[a] = p + fc3_b[0];
}

extern "C" void kernel_launch(void* const* d_in, const int* in_sizes, int n_in,
                              void* d_out, int out_size, void* d_ws, size_t ws_size,
                              hipStream_t stream) {
    const float* x      = (const float*)d_in[0];
    const int*   ei     = (const int*)  d_in[1];
    const float* ea     = (const float*)d_in[2];
    const int*   mask   = (const int*)  d_in[3];
    const float* action = (const float*)d_in[4];
    // d_in[5] = B (unused)
    const float* w1     = (const float*)d_in[6];
    const float* b1     = (const float*)d_in[7];
    const float* w2     = (const float*)d_in[8];
    const float* b2     = (const float*)d_in[9];
    const float* root   = (const float*)d_in[10];
    const float* bias   = (const float*)d_in[11];
    const float* fc1_w  = (const float*)d_in[12];
    const float* fc1_b  = (const float*)d_in[13];
    const float* fc2_w  = (const float*)d_in[14];
    const float* fc2_b  = (const float*)d_in[15];
    const float* fc3_w  = (const float*)d_in[16];
    const float* fc3_b  = (const float*)d_in[17];

    const int E = in_sizes[2] / 8;    // 800000
    const int A = in_sizes[4];        // 320

    const int* srcp = ei;
    const int* dstp = ei + E;

    // Workspace: [aggr_c A*16 f32][deg_c A i32]  (21.3 KB total)
    float* aggr  = (float*)d_ws;
    int*   deg_c = (int*)(aggr + (size_t)A * 16);
    size_t fixed_bytes = (size_t)A * 16 * 4 + (size_t)A * 4;

    const int nquad = E / 4;
    const int nblocks = (nquad + QUADS_PB - 1) / QUADS_PB;   // 391

    hipMemsetAsync(d_ws, 0, fixed_bytes, stream);
    k_fused<<<nblocks, NTHREADS, 0, stream>>>(srcp, dstp, (const int4*)dstp, nquad, E,
                                              x, ea, w1, b1, w2, b2, mask, A, aggr, deg_c);
    k_head<<<A, 64, 0, stream>>>(mask, A, action, x, aggr, deg_c,
                                 root, bias, fc1_w, fc1_b, fc2_w, fc2_b, fc3_w, fc3_b,
                                 (float*)d_out);
}